// Round 14
// baseline (199.534 us; speedup 1.0000x reference)
//
#include <hip/hip_runtime.h>
#include <hip/hip_bf16.h>

// Problem constants
#define B_N   4
#define CIN_  256
#define HH_   56
#define WW_   56
#define COUT_ 256
#define KK_   9
#define HW_   3136              // 56*56
#define KDIM  2304              // CIN_*KK_  (k index = kk*256 + ci)
#define NOFF  (B_N*18*HW_)      // 225792
#define NOUT  (B_N*COUT_*HW_)   // 3211264

typedef __attribute__((ext_vector_type(8))) short short8;   // 8 bf16 (4 VGPRs)
typedef __attribute__((ext_vector_type(4))) float float4v;  // MFMA accum

__device__ __forceinline__ short f2bf_bits(float v) {
    union { __hip_bfloat16 h; short s; } u;
    u.h = __float2bfloat16(v);
    return u.s;
}
__device__ __forceinline__ float bfbits2f(short s) {
    union { unsigned u; float f; } u2;
    u2.u = ((unsigned)(unsigned short)s) << 16;
    return u2.f;
}

// ---------------------------------------------------------------------------
// k_prep_all: 3 independent prep roles in ONE kernel (launch-gap reduction).
//   bx [0,2304):      At[cout][k=kk*256+ci] bf16   (GEMM A matrix)
//   bx [2304,2520):   owT2[ci][c*12+kk] fp32       (offset-conv weights)
//   bx [2520,3304):   xTb[b][pos][ci] bf16         (transposed x for gathers)
// ---------------------------------------------------------------------------
#define NB_AT  2304
#define NB_OWT 216
#define NB_XT  784
__global__ __launch_bounds__(256) void k_prep_all(const float* __restrict__ x,
                                                  const float* __restrict__ wgt,
                                                  const float* __restrict__ ow,
                                                  short* __restrict__ At,
                                                  float* __restrict__ owT2,
                                                  short* __restrict__ xTb) {
    __shared__ float tile[64][65];
    int bx = blockIdx.x;
    int t = threadIdx.x;
    if (bx < NB_AT) {
        int i = bx*256 + t;                  // exactly COUT_*KDIM threads
        int o = i / KDIM; int r = i % KDIM;
        int kk = r >> 8;  int ci = r & 255;
        At[i] = f2bf_bits(wgt[(size_t)(o*CIN_ + ci)*9 + kk]);
    } else if (bx < NB_AT + NB_OWT) {
        int i = (bx - NB_AT)*256 + t;        // exactly CIN_*216 threads
        int ci = i / 216; int r = i % 216;
        int c = r / 12;   int kk = r % 12;
        owT2[i] = (kk < 9) ? ow[(size_t)(c*CIN_ + ci)*9 + kk] : 0.f;
    } else {
        int g = bx - NB_AT - NB_OWT;         // 0..783
        int b = g / 196; int r = g % 196;
        int c0 = (r / 49) * 64; int p0 = (r % 49) * 64;
        int tp = t & 63;  int tc = t >> 6;
        #pragma unroll
        for (int i = 0; i < 16; ++i) {
            int ci = tc*16 + i;
            tile[ci][tp] = x[((size_t)b*CIN_ + c0 + ci)*HW_ + p0 + tp];
        }
        __syncthreads();
        #pragma unroll
        for (int i = 0; i < 16; ++i) {
            int p = tc*16 + i;
            xTb[((size_t)b*HW_ + p0 + p)*CIN_ + c0 + tp] = f2bf_bits(tile[tp][p]);
        }
    }
}

// ---------------------------------------------------------------------------
// k_offset3: 3x3 offset conv, ci-split 8 ways. DETERMINISTIC partials into
// pOff[cg] (no atomics — fp32 atomic jitter feeds floorf downstream and
// flips bilinear corners across replays; final-output atomics are OK, offset
// atomics are NOT). Weights in LDS, wave-uniform broadcast reads. ci loop
// MUST NOT unroll (r6: 256 VGPR + 1.9GB scratch spill). r13 software
// pipeline on the 3 x-row loads kept.
// ---------------------------------------------------------------------------
__global__ __launch_bounds__(256) void k_offset3(const float* __restrict__ x,
                                                 const float* __restrict__ owT2,
                                                 float* __restrict__ pOff) {
    __shared__ float smem[32*216];               // 27.6 KB: weights, then red
    int t = threadIdx.x;
    int w = t & 63;  int q = t >> 6;
    int b = blockIdx.x / HH_, h = blockIdx.x % HH_;
    int cg = blockIdx.y;                         // 0..7
    const float* xb = x + (size_t)b*CIN_*HW_;

    {
        const float* src = owT2 + (size_t)cg*32*216;
        for (int i = t; i < 32*216; i += 256) smem[i] = src[i];
    }
    __syncthreads();

    float acc[18];
    #pragma unroll
    for (int c = 0; c < 18; ++c) acc[c] = 0.f;

    int y0 = h - 1, y1 = h, y2 = h + 1;
    bool m0 = (w < WW_) && (y0 >= 0);
    bool m1 = (w < WW_);
    bool m2 = (w < WW_) && (y2 < HH_);

    const float* xp0 = xb + (size_t)(cg*32 + q*8)*HW_;
    float v0 = m0 ? xp0[y0*WW_ + w] : 0.f;
    float v1 = m1 ? xp0[y1*WW_ + w] : 0.f;
    float v2 = m2 ? xp0[y2*WW_ + w] : 0.f;

    #pragma unroll 1
    for (int i = 0; i < 8; ++i) {
        int cil = q*8 + i;                       // ci local 0..31, wave-uniform
        float n0 = 0.f, n1 = 0.f, n2 = 0.f;
        if (i < 7) {
            const float* xn = xb + (size_t)(cg*32 + cil + 1)*HW_;
            n0 = m0 ? xn[y0*WW_ + w] : 0.f;
            n1 = m1 ? xn[y1*WW_ + w] : 0.f;
            n2 = m2 ? xn[y2*WW_ + w] : 0.f;
        }
        float patch[9];
        {
            float c0 = v0;
            float l = __shfl_up(c0, 1);  if (w == 0) l = 0.f;
            float r = __shfl_down(c0, 1);        // lanes >=56 hold 0 -> col-56 pad ok
            patch[0] = l; patch[1] = c0; patch[2] = r;
            c0 = v1;
            l = __shfl_up(c0, 1);  if (w == 0) l = 0.f;
            r = __shfl_down(c0, 1);
            patch[3] = l; patch[4] = c0; patch[5] = r;
            c0 = v2;
            l = __shfl_up(c0, 1);  if (w == 0) l = 0.f;
            r = __shfl_down(c0, 1);
            patch[6] = l; patch[7] = c0; patch[8] = r;
        }
        const float* wr_ = smem + cil*216;       // wave-uniform -> LDS broadcast
        #pragma unroll
        for (int c = 0; c < 18; ++c) {
            float4 wA = *(const float4*)(wr_ + c*12);
            float4 wB = *(const float4*)(wr_ + c*12 + 4);
            float  w8 = wr_[c*12 + 8];
            acc[c] += patch[0]*wA.x + patch[1]*wA.y + patch[2]*wA.z + patch[3]*wA.w
                    + patch[4]*wB.x + patch[5]*wB.y + patch[6]*wB.z + patch[7]*wB.w
                    + patch[8]*w8;
        }
        v0 = n0; v1 = n1; v2 = n2;
    }
    __syncthreads();
    float* red = smem;                           // red[q][c][w] = q*1152+c*64+w
    #pragma unroll
    for (int c = 0; c < 18; ++c) red[q*1152 + c*64 + w] = acc[c];
    __syncthreads();
    float* pbase = pOff + (size_t)cg*NOFF;
    for (int o = t; o < 18*WW_; o += 256) {
        int c = o / WW_, w2 = o % WW_;
        float s = red[0*1152 + c*64 + w2] + red[1*1152 + c*64 + w2]
                + red[2*1152 + c*64 + w2] + red[3*1152 + c*64 + w2];
        pbase[(size_t)(b*18 + c)*HW_ + h*WW_ + w2] = s;
    }
}

// ---------------------------------------------------------------------------
// k_gemm v7: fused-sampling implicit-im2col GEMM, K-split z=3.
// r14 changes driven by cycle model (r13: LDS 72KB/block-iter vs MFMA 77cyc
// -> 7:1 LDS-pipe-bound):
//  (1) A-fragments loaded DIRECTLY FROM GLOBAL (At 1.2MB, L2-resident,
//      16 rows x 64B segments per wave-load) — sA deleted, LDS traffic
//      72 -> 24 KB/block-iter, LDS 30.7 -> 14 KB/block.
//  (2) epilogue = atomicAdd into zeroed out — pout + k_oreduce deleted
//      (77MB HBM + 1 launch). Atomics on the FINAL output are safe
//      (continuous; ~1ulp order jitter), unlike offsets (floorf).
// ---------------------------------------------------------------------------
__global__ __launch_bounds__(256) void k_gemm(const short* __restrict__ At,
                                              const short* __restrict__ xTb,
                                              const float* __restrict__ pOff,
                                              const float* __restrict__ ob,
                                              float* __restrict__ out) {
    __shared__ short sB[64*64];      // 8 KB, swizzled
    __shared__ int4   sPI[3*64];     // 3 KB  corner indices (this slice's kk)
    __shared__ float4 sPW[3*64];     // 3 KB  corner weights
    int t = threadIdx.x;
    int m0   = blockIdx.x * 128;     // 2 m-blocks
    int b    = blockIdx.y / 49;
    int posb = (blockIdx.y % 49) * 64;
    int ks   = blockIdx.z;           // 0..2 : kk in [ks*3, ks*3+3)
    int kt0  = ks * 768;
    int kend = kt0 + 768;

    // ---- bilinear params (with inline pOff reduction; fixed order) ----
    for (int e = t; e < 3*64; e += 256) {
        int kk = ks*3 + (e >> 6); int pl = e & 63;
        int pos = posb + pl;
        int h = pos / WW_, w = pos % WW_;
        size_t oy = (size_t)(b*18 + 2*kk    )*HW_ + pos;
        size_t ox = (size_t)(b*18 + 2*kk + 1)*HW_ + pos;
        float dy = ob[2*kk], dx = ob[2*kk + 1];
        #pragma unroll
        for (int cg2 = 0; cg2 < 8; ++cg2) {
            dy += pOff[(size_t)cg2*NOFF + oy];
            dx += pOff[(size_t)cg2*NOFF + ox];
        }
        float py = (float)(h - 1 + kk/3) + dy;
        float px = (float)(w - 1 + kk%3) + dx;
        float y0f = floorf(py), x0f = floorf(px);
        int y0 = (int)y0f, x0 = (int)x0f;
        float ty = py - y0f, tx = px - x0f;
        bool vy0 = (y0   >= 0) && (y0   < HH_);
        bool vy1 = (y0+1 >= 0) && (y0+1 < HH_);
        bool vx0 = (x0   >= 0) && (x0   < WW_);
        bool vx1 = (x0+1 >= 0) && (x0+1 < WW_);
        int y0c = min(max(y0,   0), HH_-1), y1c = min(max(y0+1, 0), HH_-1);
        int x0c = min(max(x0,   0), WW_-1), x1c = min(max(x0+1, 0), WW_-1);
        sPI[e] = make_int4(y0c*WW_+x0c, y0c*WW_+x1c, y1c*WW_+x0c, y1c*WW_+x1c);
        sPW[e] = make_float4((vy0 && vx0) ? (1.f-ty)*(1.f-tx) : 0.f,
                             (vy0 && vx1) ? (1.f-ty)*tx       : 0.f,
                             (vy1 && vx0) ? ty*(1.f-tx)       : 0.f,
                             (vy1 && vx1) ? ty*tx             : 0.f);
    }
    __syncthreads();                 // sPI/sPW read-only from here on

    int brow = t >> 2,  bqc = (t & 3) * 2;    // B staging: 2 chunks (32B)

    int wv = t >> 6;
    int wm = (wv >> 1) * 64;
    int wn = (wv & 1) * 32;
    int lane = t & 63;
    int lm = lane & 15;
    int qd = lane >> 4;

    float4v acc[4][2];
    #pragma unroll
    for (int i = 0; i < 4; ++i)
        #pragma unroll
        for (int j = 0; j < 2; ++j) acc[i][j] = (float4v)(0.f);

    // per-lane A pointer: row = m0+wm+i*16+lm, k-offset qd*8 within 32-chunk
    const short* gAF = At + (size_t)(m0 + wm + lm)*KDIM + qd*8;
    const short* xb  = xTb + (size_t)b*HW_*CIN_;

    short* wB[2];
    #pragma unroll
    for (int j = 0; j < 2; ++j) {
        int q = bqc + j;
        wB[j] = sB + (((brow >> 4)*8 + q)*16 + ((brow + 2*q) & 15))*8;
    }

    short8 cg[2][4];
    float4 bwv;
    // prologue: gather B corners for kt = kt0 (local kk 0)
    {
        int4 id = sPI[brow]; bwv = sPW[brow];
        #pragma unroll
        for (int j = 0; j < 2; ++j) {
            int ci0 = (bqc + j)*8;
            cg[j][0] = *(const short8*)(xb + (size_t)id.x*CIN_ + ci0);
            cg[j][1] = *(const short8*)(xb + (size_t)id.y*CIN_ + ci0);
            cg[j][2] = *(const short8*)(xb + (size_t)id.z*CIN_ + ci0);
            cg[j][3] = *(const short8*)(xb + (size_t)id.w*CIN_ + ci0);
        }
    }

    for (int kt = kt0; kt < kend; kt += 64) {
        // blend the gathered corners (identical math to standalone sampler)
        short8 pk[2];
        #pragma unroll
        for (int j = 0; j < 2; ++j)
            #pragma unroll
            for (int e = 0; e < 8; ++e)
                pk[j][e] = f2bf_bits(bwv.x*bfbits2f(cg[j][0][e])
                                   + bwv.y*bfbits2f(cg[j][1][e])
                                   + bwv.z*bfbits2f(cg[j][2][e])
                                   + bwv.w*bfbits2f(cg[j][3][e]));
        __syncthreads();                       // prev-iter sB reads done
        #pragma unroll
        for (int j = 0; j < 2; ++j) *(short8*)wB[j] = pk[j];
        __syncthreads();
        int kt2 = kt + 64;
        if (kt2 < kend) {                      // prefetch next gathers
            int kkl = (kt2 >> 8) - ks*3;       // local kk 0..2
            int4 id = sPI[kkl*64 + brow]; bwv = sPW[kkl*64 + brow];
            int cb = kt2 & 255;
            #pragma unroll
            for (int j = 0; j < 2; ++j) {
                int ci0 = cb + (bqc + j)*8;
                cg[j][0] = *(const short8*)(xb + (size_t)id.x*CIN_ + ci0);
                cg[j][1] = *(const short8*)(xb + (size_t)id.y*CIN_ + ci0);
                cg[j][2] = *(const short8*)(xb + (size_t)id.z*CIN_ + ci0);
                cg[j][3] = *(const short8*)(xb + (size_t)id.w*CIN_ + ci0);
            }
        }
        #pragma unroll
        for (int kss = 0; kss < 2; ++kss) {
            int kc = kt + kss*32;
            int qe = kss*4 + qd;
            int sw = (lm + 2*qe) & 15;
            short8 af[4], bf[2];
            #pragma unroll
            for (int i = 0; i < 4; ++i)        // A direct from global (L2-hot)
                af[i] = *(const short8*)(gAF + (size_t)i*16*KDIM + kc);
            #pragma unroll
            for (int j = 0; j < 2; ++j)
                bf[j] = *(short8*)(sB + ((((wn>>4) + j)*8 + qe)*16 + sw)*8);
            #pragma unroll
            for (int i = 0; i < 4; ++i)
                #pragma unroll
                for (int j = 0; j < 2; ++j)
                    acc[i][j] = __builtin_amdgcn_mfma_f32_16x16x32_bf16(
                                    af[i], bf[j], acc[i][j], 0, 0, 0);
        }
    }

    // epilogue: atomicAdd partials into zeroed out (final output — safe).
    // C/D layout col=lane&15 (n), row=qd*4+r (m).
    #pragma unroll
    for (int i = 0; i < 4; ++i)
        #pragma unroll
        for (int j = 0; j < 2; ++j) {
            int col = posb + wn + j*16 + lm;
            #pragma unroll
            for (int r = 0; r < 4; ++r) {
                int m = m0 + wm + i*16 + qd*4 + r;
                atomicAdd(&out[((size_t)b*COUT_ + m)*HW_ + col], acc[i][j][r]);
            }
        }
}

// ---------------------------------------------------------------------------
extern "C" void kernel_launch(void* const* d_in, const int* in_sizes, int n_in,
                              void* d_out, int out_size, void* d_ws, size_t ws_size,
                              hipStream_t stream) {
    const float* x   = (const float*)d_in[0];
    const float* wgt = (const float*)d_in[1];
    const float* ow  = (const float*)d_in[2];
    const float* ob  = (const float*)d_in[3];
    float* out = (float*)d_out;

    char* ws = (char*)d_ws;
    // ws layout (16B aligned): At | owT2 | xTb | pOff  (~15 MB; pout gone)
    short* At   = (short*)ws;                        // 589824*2  =  1179648
    float* owT2 = (float*)(ws + 1179648);            // 55296*4   =   221184
    short* xTb  = (short*)(ws + 1400832);            // 3211264*2 =  6422528
    float* pOff = (float*)(ws + 7823360);            // 8*225792*4=  7225344

    hipMemsetAsync(out, 0, (size_t)out_size*sizeof(float), stream);
    k_prep_all<<<dim3(NB_AT + NB_OWT + NB_XT), 256, 0, stream>>>(x, wgt, ow, At, owT2, xTb);
    k_offset3 <<<dim3(B_N*HH_, 8),             256, 0, stream>>>(x, owT2, pOff);
    k_gemm    <<<dim3(2, 196, 3),              256, 0, stream>>>(At, xTb, pOff, ob, out);
}

// Round 15
// 154.780 us; speedup vs baseline: 1.2891x; 1.2891x over previous
//
#include <hip/hip_runtime.h>
#include <hip/hip_bf16.h>

// Problem constants
#define B_N   4
#define CIN_  256
#define HH_   56
#define WW_   56
#define COUT_ 256
#define KK_   9
#define HW_   3136              // 56*56
#define KDIM  2304              // CIN_*KK_  (k index = kk*256 + ci)
#define NOFF  (B_N*18*HW_)      // 225792
#define NOUT  (B_N*COUT_*HW_)   // 3211264

typedef __attribute__((ext_vector_type(8))) short short8;   // 8 bf16 (4 VGPRs)
typedef __attribute__((ext_vector_type(4))) float float4v;  // MFMA accum

__device__ __forceinline__ short f2bf_bits(float v) {
    union { __hip_bfloat16 h; short s; } u;
    u.h = __float2bfloat16(v);
    return u.s;
}
__device__ __forceinline__ float bfbits2f(short s) {
    union { unsigned u; float f; } u2;
    u2.u = ((unsigned)(unsigned short)s) << 16;
    return u2.f;
}

// ---------------------------------------------------------------------------
// k_prep_all: 3 independent prep roles in ONE kernel (launch-gap reduction).
// ---------------------------------------------------------------------------
#define NB_AT  2304
#define NB_OWT 216
#define NB_XT  784
__global__ __launch_bounds__(256) void k_prep_all(const float* __restrict__ x,
                                                  const float* __restrict__ wgt,
                                                  const float* __restrict__ ow,
                                                  short* __restrict__ At,
                                                  float* __restrict__ owT2,
                                                  short* __restrict__ xTb) {
    __shared__ float tile[64][65];
    int bx = blockIdx.x;
    int t = threadIdx.x;
    if (bx < NB_AT) {
        int i = bx*256 + t;                  // exactly COUT_*KDIM threads
        int o = i / KDIM; int r = i % KDIM;
        int kk = r >> 8;  int ci = r & 255;
        At[i] = f2bf_bits(wgt[(size_t)(o*CIN_ + ci)*9 + kk]);
    } else if (bx < NB_AT + NB_OWT) {
        int i = (bx - NB_AT)*256 + t;        // exactly CIN_*216 threads
        int ci = i / 216; int r = i % 216;
        int c = r / 12;   int kk = r % 12;
        owT2[i] = (kk < 9) ? ow[(size_t)(c*CIN_ + ci)*9 + kk] : 0.f;
    } else {
        int g = bx - NB_AT - NB_OWT;         // 0..783
        int b = g / 196; int r = g % 196;
        int c0 = (r / 49) * 64; int p0 = (r % 49) * 64;
        int tp = t & 63;  int tc = t >> 6;
        #pragma unroll
        for (int i = 0; i < 16; ++i) {
            int ci = tc*16 + i;
            tile[ci][tp] = x[((size_t)b*CIN_ + c0 + ci)*HW_ + p0 + tp];
        }
        __syncthreads();
        #pragma unroll
        for (int i = 0; i < 16; ++i) {
            int p = tc*16 + i;
            xTb[((size_t)b*HW_ + p0 + p)*CIN_ + c0 + tp] = f2bf_bits(tile[tp][p]);
        }
    }
}

// ---------------------------------------------------------------------------
// k_offset3: 3x3 offset conv, ci-split 8 ways. DETERMINISTIC partials into
// pOff[cg] (no atomics — fp32 atomic jitter feeds floorf downstream and
// flips bilinear corners across replays). Weights in LDS, wave-uniform
// broadcast reads. ci loop MUST NOT unroll (r6: 256 VGPR + 1.9GB spill).
// r13 software pipeline on the 3 x-row loads kept.
// ---------------------------------------------------------------------------
__global__ __launch_bounds__(256) void k_offset3(const float* __restrict__ x,
                                                 const float* __restrict__ owT2,
                                                 float* __restrict__ pOff) {
    __shared__ float smem[32*216];               // 27.6 KB: weights, then red
    int t = threadIdx.x;
    int w = t & 63;  int q = t >> 6;
    int b = blockIdx.x / HH_, h = blockIdx.x % HH_;
    int cg = blockIdx.y;                         // 0..7
    const float* xb = x + (size_t)b*CIN_*HW_;

    {
        const float* src = owT2 + (size_t)cg*32*216;
        for (int i = t; i < 32*216; i += 256) smem[i] = src[i];
    }
    __syncthreads();

    float acc[18];
    #pragma unroll
    for (int c = 0; c < 18; ++c) acc[c] = 0.f;

    int y0 = h - 1, y1 = h, y2 = h + 1;
    bool m0 = (w < WW_) && (y0 >= 0);
    bool m1 = (w < WW_);
    bool m2 = (w < WW_) && (y2 < HH_);

    const float* xp0 = xb + (size_t)(cg*32 + q*8)*HW_;
    float v0 = m0 ? xp0[y0*WW_ + w] : 0.f;
    float v1 = m1 ? xp0[y1*WW_ + w] : 0.f;
    float v2 = m2 ? xp0[y2*WW_ + w] : 0.f;

    #pragma unroll 1
    for (int i = 0; i < 8; ++i) {
        int cil = q*8 + i;                       // ci local 0..31, wave-uniform
        float n0 = 0.f, n1 = 0.f, n2 = 0.f;
        if (i < 7) {
            const float* xn = xb + (size_t)(cg*32 + cil + 1)*HW_;
            n0 = m0 ? xn[y0*WW_ + w] : 0.f;
            n1 = m1 ? xn[y1*WW_ + w] : 0.f;
            n2 = m2 ? xn[y2*WW_ + w] : 0.f;
        }
        float patch[9];
        {
            float c0 = v0;
            float l = __shfl_up(c0, 1);  if (w == 0) l = 0.f;
            float r = __shfl_down(c0, 1);        // lanes >=56 hold 0 -> col-56 pad ok
            patch[0] = l; patch[1] = c0; patch[2] = r;
            c0 = v1;
            l = __shfl_up(c0, 1);  if (w == 0) l = 0.f;
            r = __shfl_down(c0, 1);
            patch[3] = l; patch[4] = c0; patch[5] = r;
            c0 = v2;
            l = __shfl_up(c0, 1);  if (w == 0) l = 0.f;
            r = __shfl_down(c0, 1);
            patch[6] = l; patch[7] = c0; patch[8] = r;
        }
        const float* wr_ = smem + cil*216;       // wave-uniform -> LDS broadcast
        #pragma unroll
        for (int c = 0; c < 18; ++c) {
            float4 wA = *(const float4*)(wr_ + c*12);
            float4 wB = *(const float4*)(wr_ + c*12 + 4);
            float  w8 = wr_[c*12 + 8];
            acc[c] += patch[0]*wA.x + patch[1]*wA.y + patch[2]*wA.z + patch[3]*wA.w
                    + patch[4]*wB.x + patch[5]*wB.y + patch[6]*wB.z + patch[7]*wB.w
                    + patch[8]*w8;
        }
        v0 = n0; v1 = n1; v2 = n2;
    }
    __syncthreads();
    float* red = smem;                           // red[q][c][w] = q*1152+c*64+w
    #pragma unroll
    for (int c = 0; c < 18; ++c) red[q*1152 + c*64 + w] = acc[c];
    __syncthreads();
    float* pbase = pOff + (size_t)cg*NOFF;
    for (int o = t; o < 18*WW_; o += 256) {
        int c = o / WW_, w2 = o % WW_;
        float s = red[0*1152 + c*64 + w2] + red[1*1152 + c*64 + w2]
                + red[2*1152 + c*64 + w2] + red[3*1152 + c*64 + w2];
        pbase[(size_t)(b*18 + c)*HW_ + h*WW_ + w2] = s;
    }
}

// ---------------------------------------------------------------------------
// k_gemm v8: REVERT to the proven r13 K-loop (sA+sB in LDS, register
// prefetch, pout stores — r14's A-from-global + atomic epilogue doubled the
// time: scattered VMEM feeding MFMA exposes L2 latency on the acc-serialized
// path; LDS staging exists to amortize exactly that). NEW: XCD-AWARE
// SWIZZLE — flat grid, b = (blockIdx&7)&3, so each XCD touches ONE batch's
// 1.6MB xTb slice (fits 4MB L2). r13 theory: FETCH 88MB >> 15MB working set
// = cross-XCD L2 thrash on the 460MB gather demand; 126MB HBM at 2.6TB/s
// ≈ the whole 49us.
// ---------------------------------------------------------------------------
__global__ __launch_bounds__(256) void k_gemm(const short* __restrict__ At,
                                              const short* __restrict__ xTb,
                                              const float* __restrict__ pOff,
                                              const float* __restrict__ ob,
                                              float* __restrict__ pout) {
    __shared__ short sA[128*64];     // 16 KB, swizzled
    __shared__ short sB[64*64];      // 8 KB, swizzled
    __shared__ int4   sPI[3*64];     // 3 KB  corner indices (this slice's kk)
    __shared__ float4 sPW[3*64];     // 3 KB  corner weights
    int t = threadIdx.x;

    // XCD-aware decode: xcd = id&7 -> b = xcd&3 (each XCD sees one batch).
    int idx = blockIdx.x;            // 0..1175
    int xcd = idx & 7;
    int b   = xcd & 3;
    int q   = (idx >> 3)*2 + (xcd >> 2);  // 0..293 within batch
    int m0   = (q & 1) * 128;        // 2 m-blocks
    int r2   = q >> 1;               // 0..146
    int posb = (r2 % 49) * 64;       // 49 n-tiles
    int ks   = r2 / 49;              // 0..2 : kk in [ks*3, ks*3+3)
    int kt0  = ks * 768;
    int kend = kt0 + 768;

    // ---- bilinear params (with inline pOff reduction; fixed order) ----
    for (int e = t; e < 3*64; e += 256) {
        int kk = ks*3 + (e >> 6); int pl = e & 63;
        int pos = posb + pl;
        int h = pos / WW_, w = pos % WW_;
        size_t oy = (size_t)(b*18 + 2*kk    )*HW_ + pos;
        size_t ox = (size_t)(b*18 + 2*kk + 1)*HW_ + pos;
        float dy = ob[2*kk], dx = ob[2*kk + 1];
        #pragma unroll
        for (int cg2 = 0; cg2 < 8; ++cg2) {
            dy += pOff[(size_t)cg2*NOFF + oy];
            dx += pOff[(size_t)cg2*NOFF + ox];
        }
        float py = (float)(h - 1 + kk/3) + dy;
        float px = (float)(w - 1 + kk%3) + dx;
        float y0f = floorf(py), x0f = floorf(px);
        int y0 = (int)y0f, x0 = (int)x0f;
        float ty = py - y0f, tx = px - x0f;
        bool vy0 = (y0   >= 0) && (y0   < HH_);
        bool vy1 = (y0+1 >= 0) && (y0+1 < HH_);
        bool vx0 = (x0   >= 0) && (x0   < WW_);
        bool vx1 = (x0+1 >= 0) && (x0+1 < WW_);
        int y0c = min(max(y0,   0), HH_-1), y1c = min(max(y0+1, 0), HH_-1);
        int x0c = min(max(x0,   0), WW_-1), x1c = min(max(x0+1, 0), WW_-1);
        sPI[e] = make_int4(y0c*WW_+x0c, y0c*WW_+x1c, y1c*WW_+x0c, y1c*WW_+x1c);
        sPW[e] = make_float4((vy0 && vx0) ? (1.f-ty)*(1.f-tx) : 0.f,
                             (vy0 && vx1) ? (1.f-ty)*tx       : 0.f,
                             (vy1 && vx0) ? ty*(1.f-tx)       : 0.f,
                             (vy1 && vx1) ? ty*tx             : 0.f);
    }
    __syncthreads();                 // sPI/sPW read-only from here on

    int arow = t >> 1,  aqc = (t & 1) * 4;    // A staging: 4 chunks (64B)
    int brow = t >> 2,  bqc = (t & 3) * 2;    // B staging: 2 chunks (32B)

    int wv = t >> 6;
    int wm = (wv >> 1) * 64;
    int wn = (wv & 1) * 32;
    int lane = t & 63;
    int lm = lane & 15;
    int qd = lane >> 4;

    float4v acc[4][2];
    #pragma unroll
    for (int i = 0; i < 4; ++i)
        #pragma unroll
        for (int j = 0; j < 2; ++j) acc[i][j] = (float4v)(0.f);

    const short* gA = At + (size_t)(m0 + arow)*KDIM + aqc*8;
    const short* xb = xTb + (size_t)b*HW_*CIN_;

    short* wA[4]; short* wB[2];
    #pragma unroll
    for (int j = 0; j < 4; ++j) {
        int qq = aqc + j;
        wA[j] = sA + (((arow >> 4)*8 + qq)*16 + ((arow + 2*qq) & 15))*8;
    }
    #pragma unroll
    for (int j = 0; j < 2; ++j) {
        int qq = bqc + j;
        wB[j] = sB + (((brow >> 4)*8 + qq)*16 + ((brow + 2*qq) & 15))*8;
    }

    short8 pa[4], cg[2][4];
    float4 bwv;
    // prologue: tiles for kt = kt0 (local kk 0)
    #pragma unroll
    for (int j = 0; j < 4; ++j) pa[j] = *(const short8*)(gA + kt0 + j*8);
    {
        int4 id = sPI[brow]; bwv = sPW[brow];
        #pragma unroll
        for (int j = 0; j < 2; ++j) {
            int ci0 = (bqc + j)*8;
            cg[j][0] = *(const short8*)(xb + (size_t)id.x*CIN_ + ci0);
            cg[j][1] = *(const short8*)(xb + (size_t)id.y*CIN_ + ci0);
            cg[j][2] = *(const short8*)(xb + (size_t)id.z*CIN_ + ci0);
            cg[j][3] = *(const short8*)(xb + (size_t)id.w*CIN_ + ci0);
        }
    }

    for (int kt = kt0; kt < kend; kt += 64) {
        // blend the gathered corners (identical math to standalone sampler)
        short8 pk[2];
        #pragma unroll
        for (int j = 0; j < 2; ++j)
            #pragma unroll
            for (int e = 0; e < 8; ++e)
                pk[j][e] = f2bf_bits(bwv.x*bfbits2f(cg[j][0][e])
                                   + bwv.y*bfbits2f(cg[j][1][e])
                                   + bwv.z*bfbits2f(cg[j][2][e])
                                   + bwv.w*bfbits2f(cg[j][3][e]));
        __syncthreads();                       // prev-iter LDS reads done
        #pragma unroll
        for (int j = 0; j < 4; ++j) *(short8*)wA[j] = pa[j];
        #pragma unroll
        for (int j = 0; j < 2; ++j) *(short8*)wB[j] = pk[j];
        __syncthreads();
        int kt2 = kt + 64;
        if (kt2 < kend) {                      // prefetch next tiles
            #pragma unroll
            for (int j = 0; j < 4; ++j) pa[j] = *(const short8*)(gA + kt2 + j*8);
            int kkl = (kt2 >> 8) - ks*3;       // local kk 0..2
            int4 id = sPI[kkl*64 + brow]; bwv = sPW[kkl*64 + brow];
            int cb = kt2 & 255;
            #pragma unroll
            for (int j = 0; j < 2; ++j) {
                int ci0 = cb + (bqc + j)*8;
                cg[j][0] = *(const short8*)(xb + (size_t)id.x*CIN_ + ci0);
                cg[j][1] = *(const short8*)(xb + (size_t)id.y*CIN_ + ci0);
                cg[j][2] = *(const short8*)(xb + (size_t)id.z*CIN_ + ci0);
                cg[j][3] = *(const short8*)(xb + (size_t)id.w*CIN_ + ci0);
            }
        }
        #pragma unroll
        for (int kss = 0; kss < 2; ++kss) {
            int qe = kss*4 + qd;
            int sw = (lm + 2*qe) & 15;
            short8 af[4], bf[2];
            #pragma unroll
            for (int i = 0; i < 4; ++i)
                af[i] = *(short8*)(sA + ((((wm>>4) + i)*8 + qe)*16 + sw)*8);
            #pragma unroll
            for (int j = 0; j < 2; ++j)
                bf[j] = *(short8*)(sB + ((((wn>>4) + j)*8 + qe)*16 + sw)*8);
            #pragma unroll
            for (int i = 0; i < 4; ++i)
                #pragma unroll
                for (int j = 0; j < 2; ++j)
                    acc[i][j] = __builtin_amdgcn_mfma_f32_16x16x32_bf16(
                                    af[i], bf[j], acc[i][j], 0, 0, 0);
        }
    }

    // epilogue -> per-slice partial. C/D layout col=lane&15 (n), row=qd*4+r.
    float* pbase = pout + (size_t)ks*NOUT;
    #pragma unroll
    for (int i = 0; i < 4; ++i)
        #pragma unroll
        for (int j = 0; j < 2; ++j) {
            int col = posb + wn + j*16 + lm;
            #pragma unroll
            for (int r = 0; r < 4; ++r) {
                int m = m0 + wm + i*16 + qd*4 + r;
                pbase[((size_t)b*COUT_ + m)*HW_ + col] = acc[i][j][r];
            }
        }
}

// ---------------------------------------------------------------------------
// k_oreduce: out = p0 + p1 + p2 (fixed order, bit-exact; float4 vectorized).
// ---------------------------------------------------------------------------
__global__ __launch_bounds__(256) void k_oreduce(const float* __restrict__ pout,
                                                 float* __restrict__ out) {
    int i = blockIdx.x*256 + threadIdx.x;        // float4 index, NOUT/4 total
    if (i >= NOUT/4) return;
    float4 a = ((const float4*)pout)[i];
    float4 b = ((const float4*)(pout + NOUT))[i];
    float4 c = ((const float4*)(pout + 2*(size_t)NOUT))[i];
    float4 r;
    r.x = a.x + b.x + c.x;  r.y = a.y + b.y + c.y;
    r.z = a.z + b.z + c.z;  r.w = a.w + b.w + c.w;
    ((float4*)out)[i] = r;
}

// ---------------------------------------------------------------------------
extern "C" void kernel_launch(void* const* d_in, const int* in_sizes, int n_in,
                              void* d_out, int out_size, void* d_ws, size_t ws_size,
                              hipStream_t stream) {
    const float* x   = (const float*)d_in[0];
    const float* wgt = (const float*)d_in[1];
    const float* ow  = (const float*)d_in[2];
    const float* ob  = (const float*)d_in[3];
    float* out = (float*)d_out;

    char* ws = (char*)d_ws;
    // ws layout (16B aligned): At | owT2 | xTb | pOff | pout  (~53.6MB)
    short* At   = (short*)ws;                        // 589824*2  =  1179648
    float* owT2 = (float*)(ws + 1179648);            // 55296*4   =   221184
    short* xTb  = (short*)(ws + 1400832);            // 3211264*2 =  6422528
    float* pOff = (float*)(ws + 7823360);            // 8*225792*4=  7225344
    float* pout = (float*)(ws + 15048704);           // 3*3211264*4= 38535168

    k_prep_all<<<dim3(NB_AT + NB_OWT + NB_XT), 256, 0, stream>>>(x, wgt, ow, At, owT2, xTb);
    k_offset3 <<<dim3(B_N*HH_, 8),             256, 0, stream>>>(x, owT2, pOff);
    k_gemm    <<<dim3(1176),                   256, 0, stream>>>(At, xTb, pOff, ob, pout);
    k_oreduce <<<dim3(NOUT/4/256),             256, 0, stream>>>(pout, out);
}